// Round 7
// baseline (465.688 us; speedup 1.0000x reference)
//
#include <hip/hip_runtime.h>
#include <stdint.h>

// Batched Viterbi decode: B=8192, T=512, K=12.
// r7 = r6 resubmitted verbatim (r6's bench died on infrastructure: "MI355X
// container failed twice" -- no signal, so the experiment is unchanged).
// The untested quadrant: >=2 waves/SIMD (r3's geometry: 16 lanes/row,
// 4 rows/wave, 2048 blocks) AND a mostly-VALU exchange.
// Cross-round model: r3 = LDS-pipe-bound (12 swizzles/step x 8 waves/CU ~
// 1200 cyc/step); r4/r5 = single-wave issue-bound (~7 cyc/instr at 1
// wave/SIMD, insensitive to dependency shape). Fix both: exchange = 3 XOR
// ds_swizzles (lane^4/^8/^12 -- self-inverse, direction-unambiguous, the
// guide's documented butterfly pattern) + 16 quad_perm broadcasts
// (HW-verified r0/r4). LDS ops/step/wave: 12 -> 3. Per-lane TT/SS constant
// tables map the scrambled candidate order back to absolute-state order
// (-1e30 sentinels for spare sources: absorbed adds, never max, never tie).
// Exact first-index argmax via min-select over SS (mathematically = jnp.argmax).
// Emissions / bp layout / backtrack / final: byte-identical to r3 (proven).

namespace {

constexpr int kB = 8192;
constexpr int kT = 512;
constexpr int kK = 12;
constexpr int kRows = 4;     // batch rows per wave

__device__ __forceinline__ int imin(int a, int b) { return a < b ? a : b; }

template <int OFF>
__device__ __forceinline__ float swzf(float x) {
    // ds_swizzle BitMode: src = ((l & and) | or) ^ xor, offset=(xor<<10)|(or<<5)|and
    // OFF = 0x101F / 0x201F / 0x301F: pure XOR by 4 / 8 / 12 (and=0x1F, or=0).
    return __int_as_float(__builtin_amdgcn_ds_swizzle(__float_as_int(x), OFF));
}

template <int CTRL>
__device__ __forceinline__ float dppb(float x) {
    // quad_perm broadcast of quad-lane p: CTRL = p * 0x55  [HW-verified r0/r4]
    return __int_as_float(__builtin_amdgcn_update_dpp(
        0, __float_as_int(x), CTRL, 0xf, 0xf, true));
}

__global__ __launch_bounds__(64, 2) void viterbi_fused(
    const float* __restrict__ logits,   // [B, T, K]
    const float* __restrict__ trans,    // [K, K]
    float* __restrict__ out,            // [B] scores + [B*T] paths (floats)
    uint32_t* __restrict__ bp)          // [B][64][16] dwords, 8 nibbles each
{
    const int ln    = threadIdx.x;      // 0..63
    const int grp   = ln >> 4;          // row within wave: 0..3
    const int jl    = ln & 15;          // state lane: 0..11 live, 12..15 spare
    const int q     = (jl >> 2);        // quad within 16-lane group: 0..3
    const int j     = (jl < 12) ? jl : 11;   // clamp for emission loads
    const int brow0 = blockIdx.x * kRows;
    const int b     = brow0 + grp;

    // Candidate tables. After the exchange, flat slot i = 4*k + p holds
    // prev state s = 4*(q^k) + p. TT[i] = trans[s][jl] (or -1e30 sentinel
    // for spare sources / spare destination lanes), SS[i] = s (abs index).
    float TT[16];
    int   SS[16];
#pragma unroll
    for (int k = 0; k < 4; ++k) {
#pragma unroll
        for (int p = 0; p < 4; ++p) {
            const int s = 4 * (q ^ k) + p;
            const int i = 4 * k + p;
            SS[i] = (s < 12) ? s : 63;
            TT[i] = (s < 12 && jl < 12) ? trans[s * kK + jl] : -1e30f;
        }
    }

    uint32_t* __restrict__ bpq = bp + (size_t)b * 1024 + jl;

    // per-lane emission pointer: em[b][t][j]
    const float* __restrict__ gem = logits + (size_t)b * (kT * kK) + j;

    auto ld = [&](int t) -> float {
        const int tc = (t < kT) ? t : (kT - 1);
        return gem[tc * kK];
    };

    // trellis t=0
    float nv = ld(0);
    uint32_t acc = 0u;

    // 8-step emission lookahead in registers
    float e0 = ld(1), e1 = ld(2), e2 = ld(3), e3 = ld(4);
    float e4 = ld(5), e5 = ld(6), e6 = ld(7), e7 = ld(8);

    // One Viterbi step: 3 XOR swizzles + 16 quad_perm broadcasts, 16 adds,
    // max3-friendly value tree, min-select argmax over SS (exact first-index).
#define STEP(TSTEP, EV_) do {                                                 \
    const float a1 = swzf<0x101F>(nv);   /* lane ^ 4  */                      \
    const float a2 = swzf<0x201F>(nv);   /* lane ^ 8  */                      \
    const float a3 = swzf<0x301F>(nv);   /* lane ^ 12 */                      \
    const float x0  = dppb<0x00>(nv) + TT[0];                                 \
    const float x1  = dppb<0x55>(nv) + TT[1];                                 \
    const float x2  = dppb<0xAA>(nv) + TT[2];                                 \
    const float x3  = dppb<0xFF>(nv) + TT[3];                                 \
    const float x4  = dppb<0x00>(a1) + TT[4];                                 \
    const float x5  = dppb<0x55>(a1) + TT[5];                                 \
    const float x6  = dppb<0xAA>(a1) + TT[6];                                 \
    const float x7  = dppb<0xFF>(a1) + TT[7];                                 \
    const float x8  = dppb<0x00>(a2) + TT[8];                                 \
    const float x9  = dppb<0x55>(a2) + TT[9];                                 \
    const float x10 = dppb<0xAA>(a2) + TT[10];                                \
    const float x11 = dppb<0xFF>(a2) + TT[11];                                \
    const float x12 = dppb<0x00>(a3) + TT[12];                                \
    const float x13 = dppb<0x55>(a3) + TT[13];                                \
    const float x14 = dppb<0xAA>(a3) + TT[14];                                \
    const float x15 = dppb<0xFF>(a3) + TT[15];                                \
    const float t0 = fmaxf(fmaxf(x0, x1), x2);                                \
    const float t1 = fmaxf(fmaxf(x3, x4), x5);                                \
    const float t2 = fmaxf(fmaxf(x6, x7), x8);                                \
    const float t3 = fmaxf(fmaxf(x9, x10), x11);                              \
    const float t4 = fmaxf(fmaxf(x12, x13), x14);                             \
    const float u0 = fmaxf(fmaxf(t0, t1), t2);                                \
    const float u1 = fmaxf(fmaxf(t3, t4), x15);                               \
    const float best = fmaxf(u0, u1);                                         \
    const int c0  = (x0  == best) ? SS[0]  : 63;                              \
    const int c1  = (x1  == best) ? SS[1]  : 63;                              \
    const int c2  = (x2  == best) ? SS[2]  : 63;                              \
    const int c3  = (x3  == best) ? SS[3]  : 63;                              \
    const int c4  = (x4  == best) ? SS[4]  : 63;                              \
    const int c5  = (x5  == best) ? SS[5]  : 63;                              \
    const int c6  = (x6  == best) ? SS[6]  : 63;                              \
    const int c7  = (x7  == best) ? SS[7]  : 63;                              \
    const int c8  = (x8  == best) ? SS[8]  : 63;                              \
    const int c9  = (x9  == best) ? SS[9]  : 63;                              \
    const int c10 = (x10 == best) ? SS[10] : 63;                              \
    const int c11 = (x11 == best) ? SS[11] : 63;                              \
    const int c12 = (x12 == best) ? SS[12] : 63;                              \
    const int c13 = (x13 == best) ? SS[13] : 63;                              \
    const int c14 = (x14 == best) ? SS[14] : 63;                              \
    const int c15 = (x15 == best) ? SS[15] : 63;                              \
    const int m0 = imin(imin(c0, c1), c2);                                    \
    const int m1 = imin(imin(c3, c4), c5);                                    \
    const int m2 = imin(imin(c6, c7), c8);                                    \
    const int m3 = imin(imin(c9, c10), c11);                                  \
    const int m4 = imin(imin(c12, c13), c14);                                 \
    const int w0 = imin(imin(m0, m1), m2);                                    \
    const int w1 = imin(imin(m3, m4), c15);                                   \
    const int bi = imin(w0, w1);                                              \
    nv = best + (EV_);                                                        \
    acc |= (uint32_t)bi << (4 * (((TSTEP) - 1) & 7));                         \
} while (0)

    // main: t = 1..504 in 63 sub-blocks of 8
#pragma unroll 1
    for (int sb = 0; sb < 63; ++sb) {
        const int tb = 8 * sb + 1;

        const float f0 = ld(tb + 8),  f1 = ld(tb + 9);
        const float f2 = ld(tb + 10), f3 = ld(tb + 11);
        const float f4 = ld(tb + 12), f5 = ld(tb + 13);
        const float f6 = ld(tb + 14), f7 = ld(tb + 15);

        STEP(tb + 0, e0); STEP(tb + 1, e1); STEP(tb + 2, e2); STEP(tb + 3, e3);
        STEP(tb + 4, e4); STEP(tb + 5, e5); STEP(tb + 6, e6); STEP(tb + 7, e7);

        bpq[sb * 16] = acc;     // 16 dwords per (row,block)
        acc = 0u;

        e0 = f0; e1 = f1; e2 = f2; e3 = f3;
        e4 = f4; e5 = f5; e6 = f6; e7 = f7;
    }

    // tail: t = 505..511
    STEP(505, e0); STEP(506, e1); STEP(507, e2); STEP(508, e3);
    STEP(509, e4); STEP(510, e5); STEP(511, e6);
    bpq[63 * 16] = acc;

#undef STEP

    // final 12-way max + first-index argmax (same exchange, no TT; spare
    // sources sit at ~-1e30 and can never equal best)
    float best;
    int last;
    {
        const float a1 = swzf<0x101F>(nv);
        const float a2 = swzf<0x201F>(nv);
        const float a3 = swzf<0x301F>(nv);
        const float x0  = dppb<0x00>(nv), x1  = dppb<0x55>(nv);
        const float x2  = dppb<0xAA>(nv), x3  = dppb<0xFF>(nv);
        const float x4  = dppb<0x00>(a1), x5  = dppb<0x55>(a1);
        const float x6  = dppb<0xAA>(a1), x7  = dppb<0xFF>(a1);
        const float x8  = dppb<0x00>(a2), x9  = dppb<0x55>(a2);
        const float x10 = dppb<0xAA>(a2), x11 = dppb<0xFF>(a2);
        const float x12 = dppb<0x00>(a3), x13 = dppb<0x55>(a3);
        const float x14 = dppb<0xAA>(a3), x15 = dppb<0xFF>(a3);
        const float t0 = fmaxf(fmaxf(x0, x1), x2);
        const float t1 = fmaxf(fmaxf(x3, x4), x5);
        const float t2 = fmaxf(fmaxf(x6, x7), x8);
        const float t3 = fmaxf(fmaxf(x9, x10), x11);
        const float t4 = fmaxf(fmaxf(x12, x13), x14);
        const float u0 = fmaxf(fmaxf(t0, t1), t2);
        const float u1 = fmaxf(fmaxf(t3, t4), x15);
        best = fmaxf(u0, u1);
        const int c0  = (x0  == best) ? SS[0]  : 63;
        const int c1  = (x1  == best) ? SS[1]  : 63;
        const int c2  = (x2  == best) ? SS[2]  : 63;
        const int c3  = (x3  == best) ? SS[3]  : 63;
        const int c4  = (x4  == best) ? SS[4]  : 63;
        const int c5  = (x5  == best) ? SS[5]  : 63;
        const int c6  = (x6  == best) ? SS[6]  : 63;
        const int c7  = (x7  == best) ? SS[7]  : 63;
        const int c8  = (x8  == best) ? SS[8]  : 63;
        const int c9  = (x9  == best) ? SS[9]  : 63;
        const int c10 = (x10 == best) ? SS[10] : 63;
        const int c11 = (x11 == best) ? SS[11] : 63;
        const int c12 = (x12 == best) ? SS[12] : 63;
        const int c13 = (x13 == best) ? SS[13] : 63;
        const int c14 = (x14 == best) ? SS[14] : 63;
        const int c15 = (x15 == best) ? SS[15] : 63;
        const int m0 = imin(imin(c0, c1), c2);
        const int m1 = imin(imin(c3, c4), c5);
        const int m2 = imin(imin(c6, c7), c8);
        const int m3 = imin(imin(c9, c10), c11);
        const int m4 = imin(imin(c12, c13), c14);
        const int w0 = imin(imin(m0, m1), m2);
        const int w1 = imin(imin(m3, m4), c15);
        last = imin(w0, w1);
    }

    __syncthreads();   // drain bp stores before same-wave cross-lane readback

    // Backtrack (r3-proven): per 8-step block: 12 dwords (3x dwordx4,
    // software-pipelined) + in-register 12:1 mux by tag.
#define BTS(SUB, PB) do {                                                     \
    const uint32_t e0_ = (tag & 1) ? qa.y : qa.x;                             \
    const uint32_t e1_ = (tag & 1) ? qa.w : qa.z;                             \
    const uint32_t e2_ = (tag & 1) ? qb.y : qb.x;                             \
    const uint32_t e3_ = (tag & 1) ? qb.w : qb.z;                             \
    const uint32_t e4_ = (tag & 1) ? qc.y : qc.x;                             \
    const uint32_t e5_ = (tag & 1) ? qc.w : qc.z;                             \
    const uint32_t f0_ = (tag & 2) ? e1_ : e0_;                               \
    const uint32_t f1_ = (tag & 2) ? e3_ : e2_;                               \
    const uint32_t f2_ = (tag & 2) ? e5_ : e4_;                               \
    const uint32_t g0_ = (tag & 4) ? f1_ : f0_;                               \
    const uint32_t dw_ = (tag >= 8) ? f2_ : g0_;                              \
    tag = (int)((dw_ >> (4 * (SUB))) & 0xFu);                                 \
    paths[(PB) + (SUB)] = (float)tag;                                         \
} while (0)

    if (jl == 0) {
        out[b] = best;
        float* __restrict__ paths = out + kB + (size_t)b * kT;
        paths[kT - 1] = (float)last;

        int tag = last;
        const uint4* __restrict__ rec = (const uint4*)(bp + (size_t)b * 1024);

        uint4 qa = rec[63 * 4 + 0], qb = rec[63 * 4 + 1], qc = rec[63 * 4 + 2];
        uint4 na = rec[62 * 4 + 0], nb = rec[62 * 4 + 1], nc = rec[62 * 4 + 2];

        // blk 63: subs 6..0 (s = 510..504)
        BTS(6, 504); BTS(5, 504); BTS(4, 504); BTS(3, 504);
        BTS(2, 504); BTS(1, 504); BTS(0, 504);

#pragma unroll 1
        for (int blk = 62; blk >= 0; --blk) {
            qa = na; qb = nb; qc = nc;
            if (blk > 0) {
                na = rec[blk * 4 - 4];
                nb = rec[blk * 4 - 3];
                nc = rec[blk * 4 - 2];
            }
            const int pb = blk * 8;
            BTS(7, pb); BTS(6, pb); BTS(5, pb); BTS(4, pb);
            BTS(3, pb); BTS(2, pb); BTS(1, pb); BTS(0, pb);
        }
    }
#undef BTS
}

} // namespace

extern "C" void kernel_launch(void* const* d_in, const int* in_sizes, int n_in,
                              void* d_out, int out_size, void* d_ws, size_t ws_size,
                              hipStream_t stream) {
    const float* logits = (const float*)d_in[0];   // [8192, 512, 12] f32
    const float* trans  = (const float*)d_in[1];   // [12, 12] f32
    float* out = (float*)d_out;
    uint32_t* bp = (uint32_t*)d_ws;                // 8192*64*16*4 = 33.55 MB

    const int threads = 64;                        // 1 wave, 4 rows
    const int blocks = kB / kRows;                 // 2048 blocks -> 2 waves/SIMD
    viterbi_fused<<<blocks, threads, 0, stream>>>(logits, trans, out, bp);
}